// Round 1
// baseline (230.474 us; speedup 1.0000x reference)
//
#include <hip/hip_runtime.h>

// y[i,j] = x[i,j] * w[j] + b[j], all FP32.
// x: (8192, 4096) fp32, w/b: (4096,) fp32, out: (8192, 4096) fp32.
// Pure streaming: 128 MiB read + 128 MiB write -> HBM-bound, floor ~43 us @ 6.3 TB/s.
//
// R1 changes vs baseline (one float4/thread, 32768 wg):
//  - grid-stride with 2048 wg; stride = 2048*256 = 524288 float4s, a multiple of
//    WVECS=1024 => each thread's float4-column is INVARIANT => load w/b ONCE
//    into registers (removes 2 of 3 load instructions + ~256 MB of L2 traffic).
//  - 4x unroll: 4 independent 16B loads in flight per thread (MLP).
//  - non-temporal load/store on the streamed x/out (read/write-once data);
//    w/b keep normal caching.

#define IN_FEATURES 4096
#define VEC 4
#define WVECS (IN_FEATURES / VEC)   // 1024 float4-columns, power of 2

#define BLOCK 256
#define GRID 2048                   // 256 CUs x 8; GRID % 4 == 0 so stride % WVECS == 0
#define UNROLL 4

typedef float f32x4 __attribute__((ext_vector_type(4)));

__global__ __launch_bounds__(BLOCK) void one_to_one_kernel(
        const f32x4* __restrict__ x,
        const f32x4* __restrict__ w,
        const f32x4* __restrict__ b,
        f32x4* __restrict__ out,
        int nvec) {
    const int tid    = blockIdx.x * BLOCK + (int)threadIdx.x;
    const int stride = GRID * BLOCK;           // 524288; stride % WVECS == 0

    // Column is the same for every element this thread touches (stride is a
    // multiple of WVECS) -> w/b live in registers for the whole kernel.
    const int col = tid & (WVECS - 1);
    const f32x4 wv = w[col];
    const f32x4 bv = b[col];

    int i = tid;
    // Main loop: UNROLL independent iterations in flight.
    for (; i + (UNROLL - 1) * stride < nvec; i += UNROLL * stride) {
        f32x4 xv[UNROLL];
#pragma unroll
        for (int u = 0; u < UNROLL; ++u)
            xv[u] = __builtin_nontemporal_load(&x[i + u * stride]);
#pragma unroll
        for (int u = 0; u < UNROLL; ++u) {
            f32x4 ov;
            ov.x = fmaf(xv[u].x, wv.x, bv.x);
            ov.y = fmaf(xv[u].y, wv.y, bv.y);
            ov.z = fmaf(xv[u].z, wv.z, bv.z);
            ov.w = fmaf(xv[u].w, wv.w, bv.w);
            __builtin_nontemporal_store(ov, &out[i + u * stride]);
        }
    }
    // Tail (not taken for the 8192x4096 shape: nvec = 16 * stride exactly).
    for (; i < nvec; i += stride) {
        f32x4 xv = __builtin_nontemporal_load(&x[i]);
        f32x4 ov;
        ov.x = fmaf(xv.x, wv.x, bv.x);
        ov.y = fmaf(xv.y, wv.y, bv.y);
        ov.z = fmaf(xv.z, wv.z, bv.z);
        ov.w = fmaf(xv.w, wv.w, bv.w);
        __builtin_nontemporal_store(ov, &out[i]);
    }
}

extern "C" void kernel_launch(void* const* d_in, const int* in_sizes, int n_in,
                              void* d_out, int out_size, void* d_ws, size_t ws_size,
                              hipStream_t stream) {
    const f32x4* x = (const f32x4*)d_in[0];    // setup_inputs dict order: x, weight, bias
    const f32x4* w = (const f32x4*)d_in[1];
    const f32x4* b = (const f32x4*)d_in[2];
    f32x4* out = (f32x4*)d_out;

    int nvec = out_size / VEC;                 // 33,554,432 / 4 = 8,388,608
    one_to_one_kernel<<<GRID, BLOCK, 0, stream>>>(x, w, b, out, nvec);
}